// Round 1
// baseline (504.578 us; speedup 1.0000x reference)
//
#include <hip/hip_runtime.h>
#include <stdint.h>

#define WN 343       // tokens per window
#define NH 6         // heads
#define HD 32        // head dim
#define CD 192       // channels
#define NB 128       // windows (batch)
#define NWM 32       // mask windows

typedef __attribute__((ext_vector_type(8))) short short8;
typedef __attribute__((ext_vector_type(4))) float f32x4;

__device__ __forceinline__ unsigned short f2bf(float f) {
  union { float f; uint32_t u; } v; v.f = f;
  uint32_t r = v.u + 0x7fffu + ((v.u >> 16) & 1u);
  return (unsigned short)(r >> 16);
}

__device__ __forceinline__ short8 pack8(const float* s) {
  union { short8 v; unsigned short u[8]; } pk;
#pragma unroll
  for (int i = 0; i < 8; ++i) pk.u[i] = f2bf(s[i]);
  return pk.v;
}

// ---------------- bias precompute: bias[h][n][m] = rpb_table[rel_index[n][m]][h]
__global__ __launch_bounds__(256) void bias_kernel(const int* __restrict__ rel,
                                                   const float* __restrict__ rpb,
                                                   float* __restrict__ bias) {
  int p = blockIdx.x * 256 + threadIdx.x;
  int h = blockIdx.y;
  if (p < WN * WN) {
    int idx = rel[p];
    bias[(size_t)h * (WN * WN) + p] = rpb[idx * NH + h];
  }
}

// ---------------- QKV GEMM: C[m][n] = sum_k x[m][k]*w[n][k] + b[n], split to q/k/v bf16
__global__ __launch_bounds__(256) void qkv_kernel(
    const float* __restrict__ x, const float* __restrict__ w,
    const float* __restrict__ bvec,
    unsigned short* __restrict__ qb, unsigned short* __restrict__ kb,
    unsigned short* __restrict__ vb) {
  __shared__ __align__(16) unsigned short Xs[128][40];
  __shared__ __align__(16) unsigned short Ws[64][40];
  const int tid = threadIdx.x;
  const int wave = tid >> 6, lane = tid & 63;
  const int quad = lane >> 4, c = lane & 15;
  const int m0 = blockIdx.x * 128, n0 = blockIdx.y * 64;

  f32x4 acc[2][4];
#pragma unroll
  for (int i = 0; i < 2; ++i)
#pragma unroll
    for (int j = 0; j < 4; ++j) acc[i][j] = (f32x4){0.f, 0.f, 0.f, 0.f};

  for (int kt = 0; kt < 6; ++kt) {
    const int k0 = kt * 32;
#pragma unroll
    for (int it = 0; it < 2; ++it) {
      int tq = tid + it * 256;
      int r = tq >> 2, ch = tq & 3;
      const float* src = x + (size_t)(m0 + r) * CD + k0 + ch * 8;
      alignas(16) float tmp[8];
      *(f32x4*)tmp = *(const f32x4*)src;
      *(f32x4*)(tmp + 4) = *(const f32x4*)(src + 4);
      *(short8*)&Xs[r][ch * 8] = pack8(tmp);
    }
    {
      int r = tid >> 2, ch = tid & 3;
      const float* src = w + (size_t)(n0 + r) * CD + k0 + ch * 8;
      alignas(16) float tmp[8];
      *(f32x4*)tmp = *(const f32x4*)src;
      *(f32x4*)(tmp + 4) = *(const f32x4*)(src + 4);
      *(short8*)&Ws[r][ch * 8] = pack8(tmp);
    }
    __syncthreads();
    short8 af[2], bfr[4];
#pragma unroll
    for (int i = 0; i < 2; ++i)
      af[i] = *(const short8*)&Xs[wave * 32 + i * 16 + c][quad * 8];
#pragma unroll
    for (int j = 0; j < 4; ++j)
      bfr[j] = *(const short8*)&Ws[j * 16 + c][quad * 8];
#pragma unroll
    for (int i = 0; i < 2; ++i)
#pragma unroll
      for (int j = 0; j < 4; ++j)
        acc[i][j] = __builtin_amdgcn_mfma_f32_16x16x32_bf16(af[i], bfr[j], acc[i][j], 0, 0, 0);
    __syncthreads();
  }

  const float qscale = 0.17677669529663689f;  // 32^-0.5
#pragma unroll
  for (int j = 0; j < 4; ++j) {
    const int col = n0 + j * 16 + c;
    const int s = col / CD;
    const int rem = col - s * CD;
    const int h = rem >> 5, d = rem & 31;
    unsigned short* dst = (s == 0) ? qb : ((s == 1) ? kb : vb);
    const float scl = (s == 0) ? qscale : 1.0f;
    const float bn = bvec[col];
#pragma unroll
    for (int i = 0; i < 2; ++i) {
#pragma unroll
      for (int r = 0; r < 4; ++r) {
        int m = m0 + wave * 32 + i * 16 + quad * 4 + r;
        int b = m / WN, tok = m - b * WN;
        float val = (acc[i][j][r] + bn) * scl;
        dst[(((size_t)b * NH + h) * WN + tok) * HD + d] = f2bf(val);
      }
    }
  }
}

// ---------------- fused attention: one block per (b,h); online softmax over key chunks
__global__ __launch_bounds__(256) void attn_kernel(
    const unsigned short* __restrict__ qb, const unsigned short* __restrict__ kb,
    const unsigned short* __restrict__ vb, const float* __restrict__ bias,
    const float* __restrict__ mask, unsigned short* __restrict__ ob) {
  __shared__ __align__(16) unsigned short Ks[352][40];     // [token][d], pad stride 40
  __shared__ __align__(16) unsigned short Vt[HD][360];     // [d][token], pad stride 360
  __shared__ __align__(16) unsigned short Pb[4][16][32];   // per-wave P relayout buffer
  const int h = blockIdx.x, b = blockIdx.y;
  const int wdx = b & (NWM - 1);
  const int tid = threadIdx.x;
  const int wave = tid >> 6, lane = tid & 63;
  const int quad = lane >> 4, c = lane & 15;
  const size_t base = ((size_t)b * NH + h) * (WN * HD);
  const unsigned short* q = qb + base;
  const unsigned short* k = kb + base;
  const unsigned short* v = vb + base;
  const float* bh = bias + (size_t)h * (WN * WN);
  const float* mw = mask + (size_t)wdx * (WN * WN);

  // stage K (row-major) and V (transposed) into LDS, zero the pad region
  for (int t = tid; t < WN * 4; t += 256) {
    int r = t >> 2, ch = t & 3;
    *(short8*)&Ks[r][ch * 8] = *(const short8*)(k + r * HD + ch * 8);
  }
  for (int t = tid; t < 9 * 32; t += 256) {
    int r = WN + (t >> 5), d = t & 31;
    Ks[r][d] = 0;
  }
  for (int r = tid; r < WN; r += 256) {
    const unsigned short* vr = v + r * HD;
#pragma unroll
    for (int d = 0; d < HD; ++d) Vt[d][r] = vr[d];
  }
  for (int t = tid; t < 9 * 32; t += 256) {
    int key = WN + (t % 9), d = t / 9;
    Vt[d][key] = 0;
  }
  __syncthreads();

  for (int qt = wave; qt < 22; qt += 4) {
    const int q0 = qt * 16;
    int qr = q0 + c; if (qr > WN - 1) qr = WN - 1;
    const short8 qf = *(const short8*)(q + qr * HD + quad * 8);
    f32x4 o0 = (f32x4){0.f, 0.f, 0.f, 0.f}, o1 = (f32x4){0.f, 0.f, 0.f, 0.f};
    float mrun[4], lrun[4];
    int nrow[4]; size_t rowoff[4];
#pragma unroll
    for (int r = 0; r < 4; ++r) {
      mrun[r] = -1e30f; lrun[r] = 0.f;
      int n = q0 + quad * 4 + r;
      nrow[r] = n;
      int nl = (n > WN - 1) ? (WN - 1) : n;
      rowoff[r] = (size_t)nl * WN;
    }

    for (int kc = 0; kc < 11; ++kc) {
      const int k0 = kc * 32;
      short8 kf0 = *(const short8*)&Ks[k0 + c][quad * 8];
      short8 kf1 = *(const short8*)&Ks[k0 + 16 + c][quad * 8];
      f32x4 z = (f32x4){0.f, 0.f, 0.f, 0.f};
      f32x4 s0 = __builtin_amdgcn_mfma_f32_16x16x32_bf16(qf, kf0, z, 0, 0, 0);
      f32x4 s1 = __builtin_amdgcn_mfma_f32_16x16x32_bf16(qf, kf1, z, 0, 0, 0);
      const int m0c = k0 + c, m1c = k0 + 16 + c;
#pragma unroll
      for (int r = 0; r < 4; ++r) {
        float v0 = (m0c < WN) ? s0[r] + bh[rowoff[r] + m0c] + mw[rowoff[r] + m0c] : -1e30f;
        float v1 = (m1c < WN) ? s1[r] + bh[rowoff[r] + m1c] + mw[rowoff[r] + m1c] : -1e30f;
        float mx = fmaxf(v0, v1);
        mx = fmaxf(mx, __shfl_xor(mx, 1, 16));
        mx = fmaxf(mx, __shfl_xor(mx, 2, 16));
        mx = fmaxf(mx, __shfl_xor(mx, 4, 16));
        mx = fmaxf(mx, __shfl_xor(mx, 8, 16));
        float mnew = fmaxf(mrun[r], mx);
        float alpha = __expf(mrun[r] - mnew);
        float p0 = __expf(v0 - mnew);
        float p1 = __expf(v1 - mnew);
        float ps = p0 + p1;
        ps += __shfl_xor(ps, 1, 16);
        ps += __shfl_xor(ps, 2, 16);
        ps += __shfl_xor(ps, 4, 16);
        ps += __shfl_xor(ps, 8, 16);
        lrun[r] = lrun[r] * alpha + ps;
        mrun[r] = mnew;
        o0[r] *= alpha; o1[r] *= alpha;
        Pb[wave][quad * 4 + r][c] = f2bf(p0);
        Pb[wave][quad * 4 + r][16 + c] = f2bf(p1);
      }
      __threadfence_block();  // order Pb writes (C-layout) before A-layout reads, same wave
      short8 pf = *(const short8*)&Pb[wave][c][quad * 8];
      short8 vf0 = *(const short8*)&Vt[c][k0 + quad * 8];
      short8 vf1 = *(const short8*)&Vt[16 + c][k0 + quad * 8];
      o0 = __builtin_amdgcn_mfma_f32_16x16x32_bf16(pf, vf0, o0, 0, 0, 0);
      o1 = __builtin_amdgcn_mfma_f32_16x16x32_bf16(pf, vf1, o1, 0, 0, 0);
      __threadfence_block();  // keep next iter's Pb writes after these reads
    }

#pragma unroll
    for (int r = 0; r < 4; ++r) {
      if (nrow[r] < WN) {
        float inv = 1.0f / lrun[r];
        size_t orow = ((size_t)b * WN + nrow[r]) * CD + h * HD;
        ob[orow + c] = f2bf(o0[r] * inv);
        ob[orow + 16 + c] = f2bf(o1[r] * inv);
      }
    }
  }
}

// ---------------- output projection: out[m][n] = sum_k O[m][k]*w[n][k] + b[n]  (fp32 out)
__global__ __launch_bounds__(256) void proj_kernel(
    const unsigned short* __restrict__ ob, const float* __restrict__ w,
    const float* __restrict__ bvec, float* __restrict__ out) {
  __shared__ __align__(16) unsigned short Xs[128][40];
  __shared__ __align__(16) unsigned short Ws[64][40];
  const int tid = threadIdx.x;
  const int wave = tid >> 6, lane = tid & 63;
  const int quad = lane >> 4, c = lane & 15;
  const int m0 = blockIdx.x * 128, n0 = blockIdx.y * 64;

  f32x4 acc[2][4];
#pragma unroll
  for (int i = 0; i < 2; ++i)
#pragma unroll
    for (int j = 0; j < 4; ++j) acc[i][j] = (f32x4){0.f, 0.f, 0.f, 0.f};

  for (int kt = 0; kt < 6; ++kt) {
    const int k0 = kt * 32;
#pragma unroll
    for (int it = 0; it < 2; ++it) {
      int tq = tid + it * 256;
      int r = tq >> 2, ch = tq & 3;
      *(short8*)&Xs[r][ch * 8] = *(const short8*)(ob + (size_t)(m0 + r) * CD + k0 + ch * 8);
    }
    {
      int r = tid >> 2, ch = tid & 3;
      const float* src = w + (size_t)(n0 + r) * CD + k0 + ch * 8;
      alignas(16) float tmp[8];
      *(f32x4*)tmp = *(const f32x4*)src;
      *(f32x4*)(tmp + 4) = *(const f32x4*)(src + 4);
      *(short8*)&Ws[r][ch * 8] = pack8(tmp);
    }
    __syncthreads();
    short8 af[2], bfr[4];
#pragma unroll
    for (int i = 0; i < 2; ++i)
      af[i] = *(const short8*)&Xs[wave * 32 + i * 16 + c][quad * 8];
#pragma unroll
    for (int j = 0; j < 4; ++j)
      bfr[j] = *(const short8*)&Ws[j * 16 + c][quad * 8];
#pragma unroll
    for (int i = 0; i < 2; ++i)
#pragma unroll
      for (int j = 0; j < 4; ++j)
        acc[i][j] = __builtin_amdgcn_mfma_f32_16x16x32_bf16(af[i], bfr[j], acc[i][j], 0, 0, 0);
    __syncthreads();
  }

#pragma unroll
  for (int j = 0; j < 4; ++j) {
    int col = n0 + j * 16 + c;
    float bn = bvec[col];
#pragma unroll
    for (int i = 0; i < 2; ++i) {
#pragma unroll
      for (int r = 0; r < 4; ++r) {
        int m = m0 + wave * 32 + i * 16 + quad * 4 + r;
        out[(size_t)m * CD + col] = acc[i][j][r] + bn;
      }
    }
  }
}

extern "C" void kernel_launch(void* const* d_in, const int* in_sizes, int n_in,
                              void* d_out, int out_size, void* d_ws, size_t ws_size,
                              hipStream_t stream) {
  const float* x      = (const float*)d_in[0];
  const float* mask   = (const float*)d_in[1];
  const float* qkv_w  = (const float*)d_in[2];
  const float* qkv_b  = (const float*)d_in[3];
  const float* proj_w = (const float*)d_in[4];
  const float* proj_b = (const float*)d_in[5];
  const float* rpb    = (const float*)d_in[6];
  const int*   rel    = (const int*)d_in[7];
  float* out = (float*)d_out;

  char* ws = (char*)d_ws;
  float* bias = (float*)ws;                    // 6*343*343*4 = 2,823,576 B
  size_t off = 2823680;                        // 256-aligned
  unsigned short* qb = (unsigned short*)(ws + off); off += 16859136;  // 128*6*343*32 bf16
  unsigned short* kb = (unsigned short*)(ws + off); off += 16859136;
  unsigned short* vb = (unsigned short*)(ws + off); off += 16859136;
  unsigned short* ob = (unsigned short*)(ws + off); off += 16859136; // [B][N][192] bf16

  hipLaunchKernelGGL(bias_kernel, dim3(460, 6), dim3(256), 0, stream, rel, rpb, bias);
  hipLaunchKernelGGL(qkv_kernel, dim3(343, 9), dim3(256), 0, stream,
                     x, qkv_w, qkv_b, qb, kb, vb);
  hipLaunchKernelGGL(attn_kernel, dim3(6, 128), dim3(256), 0, stream,
                     qb, kb, vb, bias, mask, ob);
  hipLaunchKernelGGL(proj_kernel, dim3(343, 3), dim3(256), 0, stream,
                     ob, proj_w, proj_b, out);
}

// Round 2
// 267.475 us; speedup vs baseline: 1.8865x; 1.8865x over previous
//
#include <hip/hip_runtime.h>
#include <stdint.h>

#define WN 343       // tokens per window
#define NH 6         // heads
#define HD 32        // head dim
#define CD 192       // channels
#define NB 128       // windows (batch)
#define NWM 32       // mask windows

typedef __attribute__((ext_vector_type(8))) short short8;
typedef __attribute__((ext_vector_type(4))) float f32x4;

__device__ __forceinline__ unsigned short f2bf(float f) {
  union { float f; uint32_t u; } v; v.f = f;
  uint32_t r = v.u + 0x7fffu + ((v.u >> 16) & 1u);
  return (unsigned short)(r >> 16);
}

__device__ __forceinline__ short8 pack8(const float* s) {
  union { short8 v; unsigned short u[8]; } pk;
#pragma unroll
  for (int i = 0; i < 8; ++i) pk.u[i] = f2bf(s[i]);
  return pk.v;
}

// ---------------- bias precompute: bias[h][n][m] = rpb_table[rel_index[n][m]][h]
__global__ __launch_bounds__(256) void bias_kernel(const int* __restrict__ rel,
                                                   const float* __restrict__ rpb,
                                                   float* __restrict__ bias) {
  int p = blockIdx.x * 256 + threadIdx.x;
  int h = blockIdx.y;
  if (p < WN * WN) {
    int idx = rel[p];
    bias[(size_t)h * (WN * WN) + p] = rpb[idx * NH + h];
  }
}

// ---------------- QKV GEMM: 128x192 tiles; C[m][n] = sum_k x[m][k]*w[n][k] + b[n]
__global__ __launch_bounds__(256) void qkv_kernel(
    const float* __restrict__ x, const float* __restrict__ w,
    const float* __restrict__ bvec,
    unsigned short* __restrict__ qb, unsigned short* __restrict__ kb,
    unsigned short* __restrict__ vb) {
  __shared__ __align__(16) unsigned short Xs[128][40];
  __shared__ __align__(16) unsigned short Ws[192][40];
  const int tid = threadIdx.x;
  const int wave = tid >> 6, lane = tid & 63;
  const int quad = lane >> 4, c = lane & 15;
  const int m0 = blockIdx.x * 128;
  const int s = blockIdx.y;            // 0=q, 1=k, 2=v
  const int n0 = s * 192;

  f32x4 acc[2][12];
#pragma unroll
  for (int i = 0; i < 2; ++i)
#pragma unroll
    for (int j = 0; j < 12; ++j) acc[i][j] = (f32x4){0.f, 0.f, 0.f, 0.f};

  for (int kt = 0; kt < 6; ++kt) {
    const int k0 = kt * 32;
#pragma unroll
    for (int it = 0; it < 2; ++it) {
      int tq = tid + it * 256;
      int r = tq >> 2, ch = tq & 3;
      const float* src = x + (size_t)(m0 + r) * CD + k0 + ch * 8;
      alignas(16) float tmp[8];
      *(f32x4*)tmp = *(const f32x4*)src;
      *(f32x4*)(tmp + 4) = *(const f32x4*)(src + 4);
      *(short8*)&Xs[r][ch * 8] = pack8(tmp);
    }
#pragma unroll
    for (int it = 0; it < 3; ++it) {
      int r = it * 64 + (tid >> 2), ch = tid & 3;
      const float* src = w + (size_t)(n0 + r) * CD + k0 + ch * 8;
      alignas(16) float tmp[8];
      *(f32x4*)tmp = *(const f32x4*)src;
      *(f32x4*)(tmp + 4) = *(const f32x4*)(src + 4);
      *(short8*)&Ws[r][ch * 8] = pack8(tmp);
    }
    __syncthreads();
    short8 af0 = *(const short8*)&Xs[wave * 32 + c][quad * 8];
    short8 af1 = *(const short8*)&Xs[wave * 32 + 16 + c][quad * 8];
#pragma unroll
    for (int j = 0; j < 12; ++j) {
      short8 bfr = *(const short8*)&Ws[j * 16 + c][quad * 8];
      acc[0][j] = __builtin_amdgcn_mfma_f32_16x16x32_bf16(af0, bfr, acc[0][j], 0, 0, 0);
      acc[1][j] = __builtin_amdgcn_mfma_f32_16x16x32_bf16(af1, bfr, acc[1][j], 0, 0, 0);
    }
    __syncthreads();
  }

  const float qscale = 0.17677669529663689f;  // 32^-0.5
  unsigned short* dst = (s == 0) ? qb : ((s == 1) ? kb : vb);
  const float scl = (s == 0) ? qscale : 1.0f;
#pragma unroll
  for (int j = 0; j < 12; ++j) {
    const int rem = j * 16 + c;          // 0..191 within this s
    const int h = rem >> 5, d = rem & 31;
    const float bn = bvec[n0 + rem];
#pragma unroll
    for (int i = 0; i < 2; ++i) {
#pragma unroll
      for (int r = 0; r < 4; ++r) {
        int m = m0 + wave * 32 + i * 16 + quad * 4 + r;
        int b = m / WN, tok = m - b * WN;
        float val = (acc[i][j][r] + bn) * scl;
        dst[(((size_t)b * NH + h) * WN + tok) * HD + d] = f2bf(val);
      }
    }
  }
}

// ---------------- fused attention, two-pass softmax (scores in registers)
__global__ __launch_bounds__(256) void attn_kernel(
    const unsigned short* __restrict__ qb, const unsigned short* __restrict__ kb,
    const unsigned short* __restrict__ vb, const float* __restrict__ bias,
    const float* __restrict__ mask, unsigned short* __restrict__ ob) {
  __shared__ __align__(16) unsigned short Ks[352][40];      // [token][d]
  __shared__ __align__(16) unsigned short Vt[HD][360];      // [d][phys-token]
  __shared__ __align__(16) unsigned short Pb[4][2][16][40]; // per-wave dbuf P, padded
  const int h = blockIdx.x, b = blockIdx.y;
  const int wdx = b & (NWM - 1);
  const int tid = threadIdx.x;
  const int wave = tid >> 6, lane = tid & 63;
  const int quad = lane >> 4, c = lane & 15;
  const size_t base = ((size_t)b * NH + h) * (WN * HD);
  const unsigned short* q = qb + base;
  const unsigned short* k = kb + base;
  const unsigned short* v = vb + base;
  const float* bh = bias + (size_t)h * (WN * WN);
  const float* mw = mask + (size_t)wdx * (WN * WN);

  // stage K row-major (zero-pad rows 343..351)
  for (int t = tid; t < WN * 4; t += 256) {
    int r = t >> 2, ch = t & 3;
    *(short8*)&Ks[r][ch * 8] = *(const short8*)(k + r * HD + ch * 8);
  }
  for (int t = tid; t < 9 * 32; t += 256) {
    int r = WN + (t >> 5), d = t & 31;
    Ks[r][d] = 0;
  }
  // stage V transposed with per-chunk key permutation phys = 2*(t&15) + (t>>4)
  for (int t = tid; t < WN; t += 256) {
    int kc = t >> 5, tt = t & 31;
    int phys = (kc << 5) + ((tt & 15) * 2 + (tt >> 4));
    const unsigned short* vr = v + t * HD;
#pragma unroll
    for (int d = 0; d < HD; ++d) Vt[d][phys] = vr[d];
  }
  for (int t = WN + tid; t < 352; t += 256) {
    int tt = t & 31;
    int phys = 320 + ((tt & 15) * 2 + (tt >> 4));
#pragma unroll
    for (int d = 0; d < HD; ++d) Vt[d][phys] = 0;
  }
  __syncthreads();

  for (int qt = wave; qt < 22; qt += 4) {
    const int q0 = qt * 16;
    int qr = q0 + c; if (qr > WN - 1) qr = WN - 1;
    const short8 qf = *(const short8*)(q + qr * HD + quad * 8);
    int rowoff[4];
#pragma unroll
    for (int r = 0; r < 4; ++r) {
      int n = q0 + quad * 4 + r;
      int nl = (n > WN - 1) ? (WN - 1) : n;
      rowoff[r] = nl * WN;
    }

    // Pass 1: QK^T all chunks into registers
    f32x4 s[22];
#pragma unroll
    for (int kc = 0; kc < 11; ++kc) {
      const int k0 = kc * 32;
      short8 kf0 = *(const short8*)&Ks[k0 + c][quad * 8];
      short8 kf1 = *(const short8*)&Ks[k0 + 16 + c][quad * 8];
      f32x4 z = (f32x4){0.f, 0.f, 0.f, 0.f};
      s[2 * kc]     = __builtin_amdgcn_mfma_f32_16x16x32_bf16(qf, kf0, z, 0, 0, 0);
      s[2 * kc + 1] = __builtin_amdgcn_mfma_f32_16x16x32_bf16(qf, kf1, z, 0, 0, 0);
    }

    // Pass 2: bias + mask (only chunk 10's upper half can be OOB)
#pragma unroll
    for (int kc = 0; kc < 11; ++kc) {
      const int col0 = kc * 32 + c;
      const int col1 = col0 + 16;
#pragma unroll
      for (int r = 0; r < 4; ++r) {
        const float* bp = bh + rowoff[r];
        const float* mp = mw + rowoff[r];
        s[2 * kc][r] += bp[col0] + mp[col0];
        if (kc < 10) {
          s[2 * kc + 1][r] += bp[col1] + mp[col1];
        } else {
          s[2 * kc + 1][r] = (col1 < WN) ? s[2 * kc + 1][r] + bp[col1] + mp[col1]
                                         : -1e30f;
        }
      }
    }

    // Pass 3: row max (one reduction for all 352 keys)
    float mx[4];
#pragma unroll
    for (int r = 0; r < 4; ++r) {
      float m = -1e30f;
#pragma unroll
      for (int t = 0; t < 22; ++t) m = fmaxf(m, s[t][r]);
      m = fmaxf(m, __shfl_xor(m, 1, 16));
      m = fmaxf(m, __shfl_xor(m, 2, 16));
      m = fmaxf(m, __shfl_xor(m, 4, 16));
      m = fmaxf(m, __shfl_xor(m, 8, 16));
      mx[r] = m;
    }

    // Pass 4: exp (unnormalized), pack bf16 pairs, accumulate row sums
    uint32_t pk[11][4];
    float l[4] = {0.f, 0.f, 0.f, 0.f};
#pragma unroll
    for (int kc = 0; kc < 11; ++kc) {
#pragma unroll
      for (int r = 0; r < 4; ++r) {
        float p0 = __expf(s[2 * kc][r] - mx[r]);
        float p1 = __expf(s[2 * kc + 1][r] - mx[r]);
        l[r] += p0 + p1;
        pk[kc][r] = (uint32_t)f2bf(p0) | ((uint32_t)f2bf(p1) << 16);
      }
    }
#pragma unroll
    for (int r = 0; r < 4; ++r) {
      float t = l[r];
      t += __shfl_xor(t, 1, 16);
      t += __shfl_xor(t, 2, 16);
      t += __shfl_xor(t, 4, 16);
      t += __shfl_xor(t, 8, 16);
      l[r] = t;
    }

    // Pass 5: PV with double-buffered P relayout (C-layout -> A-layout)
    f32x4 o0 = (f32x4){0.f, 0.f, 0.f, 0.f}, o1 = (f32x4){0.f, 0.f, 0.f, 0.f};
#pragma unroll
    for (int kc = 0; kc < 11; ++kc) {
      const int buf = kc & 1;
#pragma unroll
      for (int r = 0; r < 4; ++r)
        *(uint32_t*)&Pb[wave][buf][quad * 4 + r][2 * c] = pk[kc][r];
      __threadfence_block();  // order this wave's Pb writes before A-layout reads
      short8 pf  = *(const short8*)&Pb[wave][buf][c][quad * 8];
      short8 vf0 = *(const short8*)&Vt[c][kc * 32 + quad * 8];
      short8 vf1 = *(const short8*)&Vt[16 + c][kc * 32 + quad * 8];
      o0 = __builtin_amdgcn_mfma_f32_16x16x32_bf16(pf, vf0, o0, 0, 0, 0);
      o1 = __builtin_amdgcn_mfma_f32_16x16x32_bf16(pf, vf1, o1, 0, 0, 0);
    }

#pragma unroll
    for (int r = 0; r < 4; ++r) {
      int n = q0 + quad * 4 + r;
      if (n < WN) {
        float inv = 1.0f / l[r];
        size_t orow = ((size_t)b * WN + n) * CD + h * HD;
        ob[orow + c] = f2bf(o0[r] * inv);
        ob[orow + 16 + c] = f2bf(o1[r] * inv);
      }
    }
  }
}

// ---------------- output projection: out[m][n] = sum_k O[m][k]*w[n][k] + b[n]  (fp32 out)
__global__ __launch_bounds__(256) void proj_kernel(
    const unsigned short* __restrict__ ob, const float* __restrict__ w,
    const float* __restrict__ bvec, float* __restrict__ out) {
  __shared__ __align__(16) unsigned short Xs[128][40];
  __shared__ __align__(16) unsigned short Ws[64][40];
  const int tid = threadIdx.x;
  const int wave = tid >> 6, lane = tid & 63;
  const int quad = lane >> 4, c = lane & 15;
  const int m0 = blockIdx.x * 128, n0 = blockIdx.y * 64;

  f32x4 acc[2][4];
#pragma unroll
  for (int i = 0; i < 2; ++i)
#pragma unroll
    for (int j = 0; j < 4; ++j) acc[i][j] = (f32x4){0.f, 0.f, 0.f, 0.f};

  for (int kt = 0; kt < 6; ++kt) {
    const int k0 = kt * 32;
#pragma unroll
    for (int it = 0; it < 2; ++it) {
      int tq = tid + it * 256;
      int r = tq >> 2, ch = tq & 3;
      *(short8*)&Xs[r][ch * 8] = *(const short8*)(ob + (size_t)(m0 + r) * CD + k0 + ch * 8);
    }
    {
      int r = tid >> 2, ch = tid & 3;
      const float* src = w + (size_t)(n0 + r) * CD + k0 + ch * 8;
      alignas(16) float tmp[8];
      *(f32x4*)tmp = *(const f32x4*)src;
      *(f32x4*)(tmp + 4) = *(const f32x4*)(src + 4);
      *(short8*)&Ws[r][ch * 8] = pack8(tmp);
    }
    __syncthreads();
    short8 af[2], bfr[4];
#pragma unroll
    for (int i = 0; i < 2; ++i)
      af[i] = *(const short8*)&Xs[wave * 32 + i * 16 + c][quad * 8];
#pragma unroll
    for (int j = 0; j < 4; ++j)
      bfr[j] = *(const short8*)&Ws[j * 16 + c][quad * 8];
#pragma unroll
    for (int i = 0; i < 2; ++i)
#pragma unroll
      for (int j = 0; j < 4; ++j)
        acc[i][j] = __builtin_amdgcn_mfma_f32_16x16x32_bf16(af[i], bfr[j], acc[i][j], 0, 0, 0);
    __syncthreads();
  }

#pragma unroll
  for (int j = 0; j < 4; ++j) {
    int col = n0 + j * 16 + c;
    float bn = bvec[col];
#pragma unroll
    for (int i = 0; i < 2; ++i) {
#pragma unroll
      for (int r = 0; r < 4; ++r) {
        int m = m0 + wave * 32 + i * 16 + quad * 4 + r;
        out[(size_t)m * CD + col] = acc[i][j][r] + bn;
      }
    }
  }
}

extern "C" void kernel_launch(void* const* d_in, const int* in_sizes, int n_in,
                              void* d_out, int out_size, void* d_ws, size_t ws_size,
                              hipStream_t stream) {
  const float* x      = (const float*)d_in[0];
  const float* mask   = (const float*)d_in[1];
  const float* qkv_w  = (const float*)d_in[2];
  const float* qkv_b  = (const float*)d_in[3];
  const float* proj_w = (const float*)d_in[4];
  const float* proj_b = (const float*)d_in[5];
  const float* rpb    = (const float*)d_in[6];
  const int*   rel    = (const int*)d_in[7];
  float* out = (float*)d_out;

  char* ws = (char*)d_ws;
  float* bias = (float*)ws;                    // 6*343*343*4 = 2,823,576 B
  size_t off = 2823680;                        // 256-aligned
  unsigned short* qb = (unsigned short*)(ws + off); off += 16859136;  // 128*6*343*32 bf16
  unsigned short* kb = (unsigned short*)(ws + off); off += 16859136;
  unsigned short* vb = (unsigned short*)(ws + off); off += 16859136;
  unsigned short* ob = (unsigned short*)(ws + off); off += 16859136; // [B][N][192] bf16

  hipLaunchKernelGGL(bias_kernel, dim3(460, 6), dim3(256), 0, stream, rel, rpb, bias);
  hipLaunchKernelGGL(qkv_kernel, dim3(343, 3), dim3(256), 0, stream,
                     x, qkv_w, qkv_b, qb, kb, vb);
  hipLaunchKernelGGL(attn_kernel, dim3(6, 128), dim3(256), 0, stream,
                     qb, kb, vb, bias, mask, ob);
  hipLaunchKernelGGL(proj_kernel, dim3(343, 3), dim3(256), 0, stream,
                     ob, proj_w, proj_b, out);
}